// Round 8
// baseline (834.308 us; speedup 1.0000x reference)
//
#include <hip/hip_runtime.h>

// ---------------------------------------------------------------------------
// LSTM_Encoder: emb-concat -> 2-layer BiLSTM (H=200/dir) -> span pack
// R7b: k_span rebuilt (compile fix: use ext_vector f32x4 for nontemporal
// stores -- HIP float4 struct is rejected by the builtin). 1024 blocks
// (16 b x 64 chunks of 126 spans) x 256 thr; two 128-thread halves process
// alternating spans, zero tail is one contiguous fill, nontemporal stores
// (out never re-read). k_prep / k_gemm / k_rec byte-identical to R6.
// ---------------------------------------------------------------------------

typedef short    s16x8 __attribute__((ext_vector_type(8)));
typedef float    f32x4 __attribute__((ext_vector_type(4)));
typedef _Float16 f16x4 __attribute__((ext_vector_type(4)));

#define MFMA16(a, b, c) __builtin_amdgcn_mfma_f32_16x16x32_bf16(a, b, c, 0, 0, 0)

__device__ __forceinline__ unsigned short f2b(float f) {
    union { float f; unsigned u; } v; v.f = f;
    unsigned r = v.u + 0x7FFFu + ((v.u >> 16) & 1u);   // RNE
    return (unsigned short)(r >> 16);
}

// ---------------- fused prep: embed | cvt_wih x2 | cvt_whh | bias | lens | pad0
__global__ __launch_bounds__(256) void k_prep(
    const float* __restrict__ ext, const float* __restrict__ wrd,
    const float* __restrict__ pos, const float* __restrict__ dep,
    const float* __restrict__ ent, const float* __restrict__ iob,
    const float* __restrict__ bert,
    const int* __restrict__ wi, const int* __restrict__ pi,
    const int* __restrict__ di, const int* __restrict__ ei,
    const int* __restrict__ ii, unsigned short* __restrict__ emb,
    const float* __restrict__ wih0, unsigned short* __restrict__ wih0b,
    const float* __restrict__ wih1, unsigned short* __restrict__ wih1b,
    const float* __restrict__ whh0, unsigned short* __restrict__ whh0p,
    const float* __restrict__ whh1, unsigned short* __restrict__ whh1p,
    const float* __restrict__ bih0, const float* __restrict__ bhh0,
    float* __restrict__ bias0p,
    const float* __restrict__ bih1, const float* __restrict__ bhh1,
    float* __restrict__ bias1p,
    int* __restrict__ lens, float* __restrict__ outTail,
    unsigned short* __restrict__ out0b)
{
    const int bid = blockIdx.x, tid = threadIdx.x;

    if (bid < 2048) {                       // ---- embed
        int r = bid;
        int w  = wi[r];
        int wid = (w >= 20000) ? 1 : w;
        int p = pi[r], dd = di[r], e = ei[r], io = ii[r];
        for (int c = tid; c < 1248; c += 256) {
            float v;
            if      (c < 300)  v = ext[(size_t)w * 300 + c] + wrd[(size_t)wid * 300 + c];
            else if (c < 350)  v = pos[p * 50 + (c - 300)];
            else if (c < 400)  v = dep[dd * 50 + (c - 350)];
            else if (c < 425)  v = ent[e * 25 + (c - 400)];
            else if (c < 450)  v = iob[io * 25 + (c - 425)];
            else if (c < 1218) v = bert[(size_t)r * 768 + (c - 450)];
            else               v = 0.f;
            emb[(size_t)r * 1248 + c] = f2b(v);
        }
    } else if (bid < 5376) {                // ---- cvt_wih (both layers)
        const int lay1 = (bid >= 3712);
        const int n = bid - (lay1 ? 3712 : 2048);
        const int K  = lay1 ? 400 : 1218;
        const int Kp = lay1 ? 416 : 1248;
        const float* src = lay1 ? wih1 : wih0;
        unsigned short* dst = lay1 ? wih1b : wih0b;
        int dd = n / 832, rem = n % 832, g = rem / 208, j = rem % 208;
        bool v = (j < 200);
        const float* s = src + ((size_t)dd * 800 + g * 200 + j) * K;
        for (int c = tid; c < Kp; c += 256)
            dst[(size_t)n * Kp + c] = (v && c < K) ? f2b(s[c]) : (unsigned short)0;
    } else if (bid < 5740) {                // ---- cvt_whh (both layers)
        int old64 = (bid - 5376) * 4 + (tid >> 6);      // 0..1455
        int lane = tid & 63;
        int layer = old64 / 728, blk = old64 % 728;
        const float* src = layer ? whh1 : whh0;
        unsigned short* dst = layer ? whh1p : whh0p;
        int kf = blk % 7, tile = (blk / 7) % 52, dd = blk / 364;
        int g = tile / 13, tt = tile % 13;
        int l15 = lane & 15, q = lane >> 4;
        int jr = tt * 16 + l15;
        for (int jj = 0; jj < 8; ++jj) {
            int k = kf * 32 + q * 8 + jj;
            float v = (jr < 200 && k < 200)
                    ? src[((size_t)dd * 800 + g * 200 + jr) * 200 + k] : 0.f;
            dst[(size_t)blk * 512 + lane * 8 + jj] = f2b(v);
        }
    } else if (bid < 5754) {                // ---- bias (both layers)
        const int lay1 = (bid >= 5747);
        const int i = (bid - (lay1 ? 5747 : 5740)) * 256 + tid;
        if (i < 1664) {
            const float* bih = lay1 ? bih1 : bih0;
            const float* bhh = lay1 ? bhh1 : bhh0;
            float* outp = lay1 ? bias1p : bias0p;
            int dd = i / 832, rem = i % 832, g = rem / 208, j = rem % 208;
            outp[i] = (j < 200) ? bih[dd * 800 + g * 200 + j] + bhh[dd * 800 + g * 200 + j]
                                : 0.f;
        }
    } else if (bid < 5755) {                // ---- lens
        int b = tid;
        if (b < 16) {
            int c = 0;
            for (int l = 0; l < 128; ++l) c += (wi[b * 128 + l] != 0);
            lens[b] = c;
            outTail[b] = (float)(c - 2);
        }
    } else {                                // ---- out0b pad-col zero
        int idx = (bid - 5755) * 256 + tid;             // 0..16383
        int r = idx >> 3, pair = idx & 7;
        ((unsigned*)out0b)[r * 208 + 200 + pair] = 0u;
    }
}

// ---------------- input-projection GEMM ------------------------------------
__global__ __launch_bounds__(256) void k_gemm(
    const unsigned short* __restrict__ A, const unsigned short* __restrict__ W,
    const float* __restrict__ biasp, _Float16* __restrict__ gxf, int lda, int nkf)
{
    int wave = (blockIdx.x << 2) | (threadIdx.x >> 6);  // 0..3327
    int lane = threadIdx.x & 63;
    int l15 = lane & 15, q = lane >> 4;
    int nstrip = wave % 13;
    int ml = wave / 13;            // d*128 + l
    int l = ml & 127, d = ml >> 7;

    const int bm = ((l15 & 3) << 2) | (l15 >> 2);       // batch at M-row l15
    const unsigned short* ap = A + (size_t)(bm * 128 + l) * lda + q * 8;
    const unsigned short* wp = W + (size_t)(d * 832 + nstrip * 64 + l15) * lda + q * 8;

    f32x4 acc[4];
    #pragma unroll
    for (int t = 0; t < 4; ++t) acc[t] = 0.f;

    s16x8 a = *(const s16x8*)(ap);
    s16x8 b[4];
    #pragma unroll
    for (int t = 0; t < 4; ++t) b[t] = *(const s16x8*)(wp + (size_t)(t * 16) * lda);

    for (int kf = 0; kf < nkf - 1; ++kf) {
        s16x8 an = *(const s16x8*)(ap + (kf + 1) * 32);
        s16x8 bn[4];
        #pragma unroll
        for (int t = 0; t < 4; ++t)
            bn[t] = *(const s16x8*)(wp + (size_t)(t * 16) * lda + (kf + 1) * 32);
        #pragma unroll
        for (int t = 0; t < 4; ++t) acc[t] = MFMA16(a, b[t], acc[t]);
        a = an;
        #pragma unroll
        for (int t = 0; t < 4; ++t) b[t] = bn[t];
    }
    #pragma unroll
    for (int t = 0; t < 4; ++t) acc[t] = MFMA16(a, b[t], acc[t]);

    #pragma unroll
    for (int t = 0; t < 4; ++t) {
        float bs = biasp[d * 832 + nstrip * 64 + t * 16 + l15];
        f16x4 v;
        #pragma unroll
        for (int r = 0; r < 4; ++r) v[r] = (_Float16)(acc[t][r] + bs);
        *(f16x4*)(gxf + ((size_t)ml * 52 + nstrip * 4 + t) * 256 + lane * 4) = v;
    }
}

// ---------------- recurrence: 8 WGs = dir x 4 batch-groups ------------------
#define PHASE2(ACC, CV, HV, TT)                                                   \
  {                                                                               \
    const int j = (TT) * 16 + l15;                                                \
    const bool jv = (j < 200);                                                    \
    const int kf6 = j >> 5, qq = (j >> 3) & 3, jj = j & 7;                        \
    float gi = ACC[0][0], gf = ACC[1][0], gg = ACC[2][0], go = ACC[3][0];         \
    float si = __builtin_amdgcn_rcpf(1.f + __builtin_amdgcn_exp2f(-1.442695041f * gi)); \
    float sf = __builtin_amdgcn_rcpf(1.f + __builtin_amdgcn_exp2f(-1.442695041f * gf)); \
    float so = __builtin_amdgcn_rcpf(1.f + __builtin_amdgcn_exp2f(-1.442695041f * go)); \
    float ag = fabsf(gg);                                                         \
    float eg = __builtin_amdgcn_exp2f(-2.885390082f * ag);                        \
    float tg = copysignf((1.f - eg) * __builtin_amdgcn_rcpf(1.f + eg), gg);       \
    float cn = sf * CV + si * tg;                                                 \
    float ac = fabsf(cn);                                                         \
    float ec = __builtin_amdgcn_exp2f(-2.885390082f * ac);                        \
    float tc = copysignf((1.f - ec) * __builtin_amdgcn_rcpf(1.f + ec), cn);       \
    float hn = so * tc;                                                           \
    CV = mt ? cn : CV;                                                            \
    HV = mt ? hn : HV;                                                            \
    if (jv) {                                                                     \
      hnxt[kf6 * 512 + (qq * 16 + q * 4) * 8 + jj] = f2b(HV);                     \
      float ov = mt ? HV : 0.f;                                                   \
      if (outb) outb[(size_t)(bat * 128 + l) * 416 + d * 200 + j] = f2b(ov);      \
      if (hf) (d ? hb : hf)[(size_t)(bat * 128 + l) * 200 + j] = ov;              \
    }                                                                             \
  }

#define BARLDS()  do {                                                            \
    __builtin_amdgcn_sched_barrier(0);                                            \
    asm volatile("s_waitcnt lgkmcnt(0)" ::: "memory");                            \
    __builtin_amdgcn_s_barrier();                                                 \
    __builtin_amdgcn_sched_barrier(0);                                            \
  } while (0)

__global__ __launch_bounds__(512, 2) void k_rec(
    const _Float16* __restrict__ gxf,        // [2][128][52][256] f16 (C-frag)
    const unsigned short* __restrict__ whhp, // [2][52][7][512] bf16
    const int* __restrict__ wi,
    unsigned short* __restrict__ outb,       // bf16 [2048][416] or null
    float* __restrict__ hf, float* __restrict__ hb) // [16][128][200] or null
{
    extern __shared__ char smem[];
    unsigned short* Bl = (unsigned short*)smem;               // 61440 B
    unsigned short* h0 = (unsigned short*)(smem + 61440);     // 7168 B
    unsigned short* h1 = (unsigned short*)(smem + 68608);     // 7168 B
    unsigned*     mskL = (unsigned*)(smem + 75776);           // 512 B

    const int d = blockIdx.x >> 2, bg = blockIdx.x & 3;
    const int tid = threadIdx.x;
    const int w = tid >> 6, lane = tid & 63, l15 = lane & 15, q = lane >> 4;
    const unsigned short* Wd = whhp + (size_t)d * 186368;
    const bool two = (w < 5);
    const int bat = bg * 4 + q;              // this lane's batch

    // stage 60 LDS B tiles (strips 8-12, kf4-6, 4 gates): 3840 float4
    for (int i = tid; i < 3840; i += 512) {
        int slot = i >> 6, rr = i & 63;
        int sp = slot / 12, rem = slot % 12, kk = rem >> 2, g = rem & 3;
        ((f32x4*)Bl)[i] =
            *((const f32x4*)(Wd + (size_t)(g * 13 + 8 + sp) * 3584 + (4 + kk) * 512) + rr);
    }
    // zero both h buffers (3584 dwords); unwritten A-rows stay zero forever
    for (int i = tid; i < 3584; i += 512) ((unsigned*)h0)[i] = 0u;
    // mask bitfield per l
    if (tid < 128) {
        unsigned m = 0;
        for (int b_ = 0; b_ < 16; ++b_) m |= (wi[b_ * 128 + tid] != 0) ? (1u << b_) : 0u;
        mskL[tid] = m;
    }

    // VGPR B tiles: strip w (all 7 kf) + strip 8+w kf0-3 (dual waves)
    s16x8 Bv[4][7];
    #pragma unroll
    for (int g = 0; g < 4; ++g)
        #pragma unroll
        for (int kf = 0; kf < 7; ++kf)
            Bv[g][kf] = *(const s16x8*)(Wd + (size_t)(g * 13 + w) * 3584 + kf * 512 + lane * 8);
    s16x8 Bv2[4][4];
    if (two) {
        #pragma unroll
        for (int g = 0; g < 4; ++g)
            #pragma unroll
            for (int kf = 0; kf < 4; ++kf)
                Bv2[g][kf] = *(const s16x8*)(Wd + (size_t)(g * 13 + 8 + w) * 3584 + kf * 512 + lane * 8);
    }

    float cs0 = 0.f, hv0 = 0.f, cs1 = 0.f, hv1 = 0.f;
    _Float16 gx0[4], gx1[4];
    {   // prefetch step 0 gx (scalar f16 at register slot bg)
        const int l0 = d ? 127 : 0;
        const _Float16* gp = gxf + (size_t)(d * 128 + l0) * 13312 + lane * 4 + bg;
        #pragma unroll
        for (int g = 0; g < 4; ++g) gx0[g] = gp[(g * 13 + w) * 256];
        if (two) {
            #pragma unroll
            for (int g = 0; g < 4; ++g) gx1[g] = gp[(g * 13 + 8 + w) * 256];
        }
    }

    __syncthreads();

    for (int t = 0; t < 128; ++t) {
        const int l = d ? 127 - t : t;
        const unsigned short* hcur = (t & 1) ? h1 : h0;
        unsigned short*       hnxt = (t & 1) ? h0 : h1;
        const unsigned mb = mskL[l];
        const bool mt = (mb >> bat) & 1;

        f32x4 acc0[4], acc1[4];
        {   // kf = 0 : C operand = prefetched gx in register 0, rows r>0 zero
            s16x8 a = *(const s16x8*)(hcur + lane * 8);
            #pragma unroll
            for (int g = 0; g < 4; ++g) {
                f32x4 ci;
                ci[0] = (float)gx0[g]; ci[1] = 0.f; ci[2] = 0.f; ci[3] = 0.f;
                acc0[g] = MFMA16(a, Bv[g][0], ci);
            }
            if (two) {
                #pragma unroll
                for (int g = 0; g < 4; ++g) {
                    f32x4 ci;
                    ci[0] = (float)gx1[g]; ci[1] = 0.f; ci[2] = 0.f; ci[3] = 0.f;
                    acc1[g] = MFMA16(a, Bv2[g][0], ci);
                }
            }
        }
        // prefetch next step's gx (consumed next iteration; no forced drain)
        {
            const int tn = (t < 127) ? t + 1 : 127;
            const int ln = d ? 127 - tn : tn;
            const _Float16* gp = gxf + (size_t)(d * 128 + ln) * 13312 + lane * 4 + bg;
            #pragma unroll
            for (int g = 0; g < 4; ++g) gx0[g] = gp[(g * 13 + w) * 256];
            if (two) {
                #pragma unroll
                for (int g = 0; g < 4; ++g) gx1[g] = gp[(g * 13 + 8 + w) * 256];
            }
        }
        #pragma unroll
        for (int kf = 1; kf < 7; ++kf) {
            s16x8 a = *(const s16x8*)(hcur + kf * 512 + lane * 8);
            #pragma unroll
            for (int g = 0; g < 4; ++g) acc0[g] = MFMA16(a, Bv[g][kf], acc0[g]);
            if (two) {
                if (kf < 4) {
                    #pragma unroll
                    for (int g = 0; g < 4; ++g) acc1[g] = MFMA16(a, Bv2[g][kf], acc1[g]);
                } else {
                    #pragma unroll
                    for (int g = 0; g < 4; ++g) {
                        s16x8 b = *(const s16x8*)(Bl + (size_t)((w * 12 + (kf - 4) * 4 + g)) * 512 + lane * 8);
                        acc1[g] = MFMA16(a, b, acc1[g]);
                    }
                }
            }
        }

        PHASE2(acc0, cs0, hv0, w)
        if (two) PHASE2(acc1, cs1, hv1, 8 + w)

        BARLDS();
    }
}

// ---------------- span pack ------------------------------------------------
// 1024 blocks = 16 b x 64 chunks of 126 spans. Two 128-thread halves work
// alternating spans (i,j wave-uniform); zero tail is one contiguous fill.
__global__ __launch_bounds__(256) void k_span(
    const float* __restrict__ hf, const float* __restrict__ hb,
    const int* __restrict__ lens, float* __restrict__ out)
{
    const int b  = blockIdx.x >> 6;
    const int nb = blockIdx.x & 63;
    const int tid = threadIdx.x;
    const int s0 = nb * 126;
    const int s1 = (s0 + 126 < 8001) ? s0 + 126 : 8001;
    const int len = lens[b];
    const int M = len - 2;
    const int np = M * (M + 1) / 2;

    const int h = tid >> 7, tl = tid & 127;

    // compute phase: spans s in [s0, min(s1,np)), half h takes s0+h, s0+h+2, ...
    const int cend = (s1 < np) ? s1 : np;
    for (int s = s0 + h; s < cend; s += 2) {
        float disc = (float)((2 * M + 1) * (2 * M + 1) - 8 * s);
        int i = (int)(((float)(2 * M + 1) - sqrtf(disc)) * 0.5f);
        if (i < 0) i = 0;
        if (i > M - 1) i = M - 1;
        #define PREF(x) ((x) * M - (x) * ((x) - 1) / 2)
        while (i > 0 && PREF(i) > s) --i;
        while (PREF(i + 1) <= s) ++i;
        int j = i + 1 + (s - PREF(i));
        #undef PREF

        if (tl < 100) {
            f32x4* orow = (f32x4*)(out + ((size_t)b * 8001 + s) * 400);
            f32x4 aa, bb;
            if (tl < 50) {
                aa = ((const f32x4*)(hf + (size_t)(b * 128 + j) * 200))[tl];
                bb = ((const f32x4*)(hf + (size_t)(b * 128 + i) * 200))[tl];
            } else {
                int t2 = tl - 50;
                aa = ((const f32x4*)(hb + (size_t)(b * 128 + i + 1) * 200))[t2];
                bb = ((const f32x4*)(hb + (size_t)(b * 128 + j + 1) * 200))[t2];
            }
            f32x4 rr = aa - bb;
            __builtin_nontemporal_store(rr, orow + tl);
        }
    }

    // zero phase: spans [max(s0,np), s1) as one contiguous f32x4 fill
    int zs = (s0 > np) ? s0 : np;
    if (zs < s1) {
        f32x4 z = 0.f;
        f32x4* zp = (f32x4*)(out + ((size_t)b * 8001 + zs) * 400);
        const int cnt = (s1 - zs) * 100;     // f32x4 count
        for (int idx = tid; idx < cnt; idx += 256)
            __builtin_nontemporal_store(z, zp + idx);
    }
}

// ---------------------------------------------------------------------------
extern "C" void kernel_launch(void* const* d_in, const int* in_sizes, int n_in,
                              void* d_out, int out_size, void* d_ws, size_t ws_size,
                              hipStream_t stream)
{
    const float* ext  = (const float*)d_in[0];
    const float* wrd  = (const float*)d_in[1];
    const float* pos  = (const float*)d_in[2];
    const float* dep  = (const float*)d_in[3];
    const float* ent  = (const float*)d_in[4];
    const float* iob  = (const float*)d_in[5];
    const float* wih0 = (const float*)d_in[6];
    const float* whh0 = (const float*)d_in[7];
    const float* bih0 = (const float*)d_in[8];
    const float* bhh0 = (const float*)d_in[9];
    const float* wih1 = (const float*)d_in[10];
    const float* whh1 = (const float*)d_in[11];
    const float* bih1 = (const float*)d_in[12];
    const float* bhh1 = (const float*)d_in[13];
    const float* bert = (const float*)d_in[14];
    const int* wi = (const int*)d_in[15];
    const int* pi = (const int*)d_in[16];
    const int* di = (const int*)d_in[17];
    const int* ei = (const int*)d_in[18];
    const int* ii = (const int*)d_in[19];
    float* out = (float*)d_out;

    char* ws = (char*)d_ws;
    unsigned short* emb    = (unsigned short*)(ws + 0);          // 5,111,808
    unsigned short* wih0b  = (unsigned short*)(ws + 5111808);    // 4,153,344
    unsigned short* wih1b  = (unsigned short*)(ws + 9265152);    // 1,384,448
    unsigned short* whh0p  = (unsigned short*)(ws + 10649600);   //   745,472
    unsigned short* whh1p  = (unsigned short*)(ws + 11395072);   //   745,472
    float*          bias0p = (float*)(ws + 12140544);            //     6,656
    float*          bias1p = (float*)(ws + 12147200);            //     6,656
    int*            lens   = (int*)(ws + 12153856);              //        64
    _Float16*       gxf0   = (_Float16*)(ws + 12153920);         // 6,815,744
    _Float16*       gxf1   = (_Float16*)(ws + 18969664);         // 6,815,744
    unsigned short* out0b  = (unsigned short*)(ws + 25785408);   // 1,703,936
    float*          hfv    = (float*)(ws + 27489344);            // 1,638,400
    float*          hbv    = (float*)(ws + 29127744);            // 1,638,400 (end 30,766,144)

    (void)hipFuncSetAttribute((const void*)k_rec,
                              hipFuncAttributeMaxDynamicSharedMemorySize, 76288);

    k_prep<<<5819, 256, 0, stream>>>(ext, wrd, pos, dep, ent, iob, bert,
                                     wi, pi, di, ei, ii, emb,
                                     wih0, wih0b, wih1, wih1b,
                                     whh0, whh0p, whh1, whh1p,
                                     bih0, bhh0, bias0p, bih1, bhh1, bias1p,
                                     lens, out + 51206400, out0b);

    k_gemm<<<832, 256, 0, stream>>>(emb, wih0b, bias0p, gxf0, 1248, 39);
    k_rec <<<8, 512, 76288, stream>>>(gxf0, whh0p, wi, out0b, nullptr, nullptr);
    k_gemm<<<832, 256, 0, stream>>>(out0b, wih1b, bias1p, gxf1, 416, 13);
    k_rec <<<8, 512, 76288, stream>>>(gxf1, whh1p, wi, nullptr, hfv, hbv);
    k_span<<<16 * 64, 256, 0, stream>>>(hfv, hbv, lens, out);
}

// Round 10
// 768.419 us; speedup vs baseline: 1.0857x; 1.0857x over previous
//
#include <hip/hip_runtime.h>

// ---------------------------------------------------------------------------
// LSTM_Encoder: emb-concat -> 2-layer BiLSTM (H=200/dir) -> span pack
// R8: 16-wave k_rec, spill-free. R3's 1024-thread attempt failed only on
// register budget (launch_bounds(1024) w/o min-waves -> 64-reg cap -> spill).
// Fixed: __launch_bounds__(1024,4) -> 128-reg cap; Bv[4][4] kf0-3 + Bv4[2]
// (kf4 g0-1) in regs (72), kf4 g2-3 + kf5-6 in LDS (130 tiles, 133 KB; LDS
// total 148 KB). 13 compute waves own ONE strip each (no dual-wave convoy,
// single PHASE2, 4 waves/SIMD latency hiding); waves 13-15 idle at barriers.
// k_prep / k_gemm / k_span identical to R7b.
// ---------------------------------------------------------------------------

typedef short    s16x8 __attribute__((ext_vector_type(8)));
typedef float    f32x4 __attribute__((ext_vector_type(4)));
typedef _Float16 f16x4 __attribute__((ext_vector_type(4)));

#define MFMA16(a, b, c) __builtin_amdgcn_mfma_f32_16x16x32_bf16(a, b, c, 0, 0, 0)

__device__ __forceinline__ unsigned short f2b(float f) {
    union { float f; unsigned u; } v; v.f = f;
    unsigned r = v.u + 0x7FFFu + ((v.u >> 16) & 1u);   // RNE
    return (unsigned short)(r >> 16);
}

// ---------------- fused prep: embed | cvt_wih x2 | cvt_whh | bias | lens | pad0
__global__ __launch_bounds__(256) void k_prep(
    const float* __restrict__ ext, const float* __restrict__ wrd,
    const float* __restrict__ pos, const float* __restrict__ dep,
    const float* __restrict__ ent, const float* __restrict__ iob,
    const float* __restrict__ bert,
    const int* __restrict__ wi, const int* __restrict__ pi,
    const int* __restrict__ di, const int* __restrict__ ei,
    const int* __restrict__ ii, unsigned short* __restrict__ emb,
    const float* __restrict__ wih0, unsigned short* __restrict__ wih0b,
    const float* __restrict__ wih1, unsigned short* __restrict__ wih1b,
    const float* __restrict__ whh0, unsigned short* __restrict__ whh0p,
    const float* __restrict__ whh1, unsigned short* __restrict__ whh1p,
    const float* __restrict__ bih0, const float* __restrict__ bhh0,
    float* __restrict__ bias0p,
    const float* __restrict__ bih1, const float* __restrict__ bhh1,
    float* __restrict__ bias1p,
    int* __restrict__ lens, float* __restrict__ outTail,
    unsigned short* __restrict__ out0b)
{
    const int bid = blockIdx.x, tid = threadIdx.x;

    if (bid < 2048) {                       // ---- embed
        int r = bid;
        int w  = wi[r];
        int wid = (w >= 20000) ? 1 : w;
        int p = pi[r], dd = di[r], e = ei[r], io = ii[r];
        for (int c = tid; c < 1248; c += 256) {
            float v;
            if      (c < 300)  v = ext[(size_t)w * 300 + c] + wrd[(size_t)wid * 300 + c];
            else if (c < 350)  v = pos[p * 50 + (c - 300)];
            else if (c < 400)  v = dep[dd * 50 + (c - 350)];
            else if (c < 425)  v = ent[e * 25 + (c - 400)];
            else if (c < 450)  v = iob[io * 25 + (c - 425)];
            else if (c < 1218) v = bert[(size_t)r * 768 + (c - 450)];
            else               v = 0.f;
            emb[(size_t)r * 1248 + c] = f2b(v);
        }
    } else if (bid < 5376) {                // ---- cvt_wih (both layers)
        const int lay1 = (bid >= 3712);
        const int n = bid - (lay1 ? 3712 : 2048);
        const int K  = lay1 ? 400 : 1218;
        const int Kp = lay1 ? 416 : 1248;
        const float* src = lay1 ? wih1 : wih0;
        unsigned short* dst = lay1 ? wih1b : wih0b;
        int dd = n / 832, rem = n % 832, g = rem / 208, j = rem % 208;
        bool v = (j < 200);
        const float* s = src + ((size_t)dd * 800 + g * 200 + j) * K;
        for (int c = tid; c < Kp; c += 256)
            dst[(size_t)n * Kp + c] = (v && c < K) ? f2b(s[c]) : (unsigned short)0;
    } else if (bid < 5740) {                // ---- cvt_whh (both layers)
        int old64 = (bid - 5376) * 4 + (tid >> 6);      // 0..1455
        int lane = tid & 63;
        int layer = old64 / 728, blk = old64 % 728;
        const float* src = layer ? whh1 : whh0;
        unsigned short* dst = layer ? whh1p : whh0p;
        int kf = blk % 7, tile = (blk / 7) % 52, dd = blk / 364;
        int g = tile / 13, tt = tile % 13;
        int l15 = lane & 15, q = lane >> 4;
        int jr = tt * 16 + l15;
        for (int jj = 0; jj < 8; ++jj) {
            int k = kf * 32 + q * 8 + jj;
            float v = (jr < 200 && k < 200)
                    ? src[((size_t)dd * 800 + g * 200 + jr) * 200 + k] : 0.f;
            dst[(size_t)blk * 512 + lane * 8 + jj] = f2b(v);
        }
    } else if (bid < 5754) {                // ---- bias (both layers)
        const int lay1 = (bid >= 5747);
        const int i = (bid - (lay1 ? 5747 : 5740)) * 256 + tid;
        if (i < 1664) {
            const float* bih = lay1 ? bih1 : bih0;
            const float* bhh = lay1 ? bhh1 : bhh0;
            float* outp = lay1 ? bias1p : bias0p;
            int dd = i / 832, rem = i % 832, g = rem / 208, j = rem % 208;
            outp[i] = (j < 200) ? bih[dd * 800 + g * 200 + j] + bhh[dd * 800 + g * 200 + j]
                                : 0.f;
        }
    } else if (bid < 5755) {                // ---- lens
        int b = tid;
        if (b < 16) {
            int c = 0;
            for (int l = 0; l < 128; ++l) c += (wi[b * 128 + l] != 0);
            lens[b] = c;
            outTail[b] = (float)(c - 2);
        }
    } else {                                // ---- out0b pad-col zero
        int idx = (bid - 5755) * 256 + tid;             // 0..16383
        int r = idx >> 3, pair = idx & 7;
        ((unsigned*)out0b)[r * 208 + 200 + pair] = 0u;
    }
}

// ---------------- input-projection GEMM ------------------------------------
__global__ __launch_bounds__(256) void k_gemm(
    const unsigned short* __restrict__ A, const unsigned short* __restrict__ W,
    const float* __restrict__ biasp, _Float16* __restrict__ gxf, int lda, int nkf)
{
    int wave = (blockIdx.x << 2) | (threadIdx.x >> 6);  // 0..3327
    int lane = threadIdx.x & 63;
    int l15 = lane & 15, q = lane >> 4;
    int nstrip = wave % 13;
    int ml = wave / 13;            // d*128 + l
    int l = ml & 127, d = ml >> 7;

    const int bm = ((l15 & 3) << 2) | (l15 >> 2);       // batch at M-row l15
    const unsigned short* ap = A + (size_t)(bm * 128 + l) * lda + q * 8;
    const unsigned short* wp = W + (size_t)(d * 832 + nstrip * 64 + l15) * lda + q * 8;

    f32x4 acc[4];
    #pragma unroll
    for (int t = 0; t < 4; ++t) acc[t] = 0.f;

    s16x8 a = *(const s16x8*)(ap);
    s16x8 b[4];
    #pragma unroll
    for (int t = 0; t < 4; ++t) b[t] = *(const s16x8*)(wp + (size_t)(t * 16) * lda);

    for (int kf = 0; kf < nkf - 1; ++kf) {
        s16x8 an = *(const s16x8*)(ap + (kf + 1) * 32);
        s16x8 bn[4];
        #pragma unroll
        for (int t = 0; t < 4; ++t)
            bn[t] = *(const s16x8*)(wp + (size_t)(t * 16) * lda + (kf + 1) * 32);
        #pragma unroll
        for (int t = 0; t < 4; ++t) acc[t] = MFMA16(a, b[t], acc[t]);
        a = an;
        #pragma unroll
        for (int t = 0; t < 4; ++t) b[t] = bn[t];
    }
    #pragma unroll
    for (int t = 0; t < 4; ++t) acc[t] = MFMA16(a, b[t], acc[t]);

    #pragma unroll
    for (int t = 0; t < 4; ++t) {
        float bs = biasp[d * 832 + nstrip * 64 + t * 16 + l15];
        f16x4 v;
        #pragma unroll
        for (int r = 0; r < 4; ++r) v[r] = (_Float16)(acc[t][r] + bs);
        *(f16x4*)(gxf + ((size_t)ml * 52 + nstrip * 4 + t) * 256 + lane * 4) = v;
    }
}

// ---------------- recurrence: 8 WGs = dir x 4 batch-groups ------------------
// 1024 threads (16 waves). Waves 0..12 own ONE strip each: B kf0-3 all gates
// + kf4 gates 0-1 in VGPRs (72), kf4 gates 2-3 + kf5-6 all gates from LDS
// (130 tiles). Waves 13-15 barrier-only. 4 batches at A-rows {0,4,8,12} ->
// C register 0. LDS: Bl 133120 | h0/h1 2x7168 | mask 512 = 147968.
#define PHASE2(ACC, CV, HV, TT)                                                   \
  {                                                                               \
    const int j = (TT) * 16 + l15;                                                \
    const bool jv = (j < 200);                                                    \
    const int kf6 = j >> 5, qq = (j >> 3) & 3, jj = j & 7;                        \
    float gi = ACC[0][0], gf = ACC[1][0], gg = ACC[2][0], go = ACC[3][0];         \
    float si = __builtin_amdgcn_rcpf(1.f + __builtin_amdgcn_exp2f(-1.442695041f * gi)); \
    float sf = __builtin_amdgcn_rcpf(1.f + __builtin_amdgcn_exp2f(-1.442695041f * gf)); \
    float so = __builtin_amdgcn_rcpf(1.f + __builtin_amdgcn_exp2f(-1.442695041f * go)); \
    float ag = fabsf(gg);                                                         \
    float eg = __builtin_amdgcn_exp2f(-2.885390082f * ag);                        \
    float tg = copysignf((1.f - eg) * __builtin_amdgcn_rcpf(1.f + eg), gg);       \
    float cn = sf * CV + si * tg;                                                 \
    float ac = fabsf(cn);                                                         \
    float ec = __builtin_amdgcn_exp2f(-2.885390082f * ac);                        \
    float tc = copysignf((1.f - ec) * __builtin_amdgcn_rcpf(1.f + ec), cn);       \
    float hn = so * tc;                                                           \
    CV = mt ? cn : CV;                                                            \
    HV = mt ? hn : HV;                                                            \
    if (jv) {                                                                     \
      hnxt[kf6 * 512 + (qq * 16 + q * 4) * 8 + jj] = f2b(HV);                     \
      float ov = mt ? HV : 0.f;                                                   \
      if (outb) outb[(size_t)(bat * 128 + l) * 416 + d * 200 + j] = f2b(ov);      \
      if (hf) (d ? hb : hf)[(size_t)(bat * 128 + l) * 200 + j] = ov;              \
    }                                                                             \
  }

// barrier draining LDS only (hnxt visibility); gx loads are consumed by the
// issuing wave (per-wave vmcnt), global stores are never read in-kernel.
#define BARLDS()  do {                                                            \
    __builtin_amdgcn_sched_barrier(0);                                            \
    asm volatile("s_waitcnt lgkmcnt(0)" ::: "memory");                            \
    __builtin_amdgcn_s_barrier();                                                 \
    __builtin_amdgcn_sched_barrier(0);                                            \
  } while (0)

__global__ __launch_bounds__(1024, 4) void k_rec(
    const _Float16* __restrict__ gxf,        // [2][128][52][256] f16 (C-frag)
    const unsigned short* __restrict__ whhp, // [2][52][7][512] bf16
    const int* __restrict__ wi,
    unsigned short* __restrict__ outb,       // bf16 [2048][416] or null
    float* __restrict__ hf, float* __restrict__ hb) // [16][128][200] or null
{
    extern __shared__ char smem[];
    unsigned short* Bl = (unsigned short*)smem;               // 133120 B (130 tiles)
    unsigned short* h0 = (unsigned short*)(smem + 133120);    // 7168 B
    unsigned short* h1 = (unsigned short*)(smem + 140288);    // 7168 B
    unsigned*     mskL = (unsigned*)(smem + 147456);          // 512 B

    const int d = blockIdx.x >> 2, bg = blockIdx.x & 3;
    const int tid = threadIdx.x;
    const int w = tid >> 6, lane = tid & 63, l15 = lane & 15, q = lane >> 4;
    const unsigned short* Wd = whhp + (size_t)d * 186368;
    const int bat = bg * 4 + q;              // this lane's batch

    // stage 130 LDS B tiles (8320 f32x4):
    //   slot<104: slot=(sp*4+g)*2+kk -> tile (g*13+sp), kf 5+kk
    //   slot>=104: s2=slot-104: sp=s2>>1, g=2+(s2&1), kf 4
    for (int i = tid; i < 8320; i += 1024) {
        int slot = i >> 6, rr = i & 63;
        const unsigned short* src;
        if (slot < 104) {
            int sp = slot >> 3, g = (slot >> 1) & 3, kk = slot & 1;
            src = Wd + (size_t)(g * 13 + sp) * 3584 + (5 + kk) * 512 + rr * 8;
        } else {
            int s2 = slot - 104;
            int sp = s2 >> 1, g = 2 + (s2 & 1);
            src = Wd + (size_t)(g * 13 + sp) * 3584 + 4 * 512 + rr * 8;
        }
        ((f32x4*)Bl)[i] = *(const f32x4*)src;
    }
    // zero both h buffers (3584 dwords); unwritten A-rows stay zero forever
    for (int i = tid; i < 3584; i += 1024) ((unsigned*)h0)[i] = 0u;
    // mask bitfield per l
    if (tid < 128) {
        unsigned m = 0;
        for (int b_ = 0; b_ < 16; ++b_) m |= (wi[b_ * 128 + tid] != 0) ? (1u << b_) : 0u;
        mskL[tid] = m;
    }

    if (w < 13) {
        // VGPR B tiles: strip w, kf0-3 all gates + kf4 gates 0-1
        s16x8 Bv[4][4];
        #pragma unroll
        for (int g = 0; g < 4; ++g)
            #pragma unroll
            for (int kf = 0; kf < 4; ++kf)
                Bv[g][kf] = *(const s16x8*)(Wd + (size_t)(g * 13 + w) * 3584 + kf * 512 + lane * 8);
        s16x8 Bv4[2];
        #pragma unroll
        for (int g = 0; g < 2; ++g)
            Bv4[g] = *(const s16x8*)(Wd + (size_t)(g * 13 + w) * 3584 + 4 * 512 + lane * 8);

        float cs0 = 0.f, hv0 = 0.f;
        _Float16 gx0[4];
        {   // prefetch step 0 gx (scalar f16 at register slot bg)
            const int l0 = d ? 127 : 0;
            const _Float16* gp = gxf + (size_t)(d * 128 + l0) * 13312 + lane * 4 + bg;
            #pragma unroll
            for (int g = 0; g < 4; ++g) gx0[g] = gp[(g * 13 + w) * 256];
        }

        __syncthreads();

        for (int t = 0; t < 128; ++t) {
            const int l = d ? 127 - t : t;
            const unsigned short* hcur = (t & 1) ? h1 : h0;
            unsigned short*       hnxt = (t & 1) ? h0 : h1;
            const unsigned mb = mskL[l];
            const bool mt = (mb >> bat) & 1;

            f32x4 acc[4];
            {   // kf = 0 : C operand = prefetched gx in register 0, rows r>0 zero
                s16x8 a = *(const s16x8*)(hcur + lane * 8);
                #pragma unroll
                for (int g = 0; g < 4; ++g) {
                    f32x4 ci;
                    ci[0] = (float)gx0[g]; ci[1] = 0.f; ci[2] = 0.f; ci[3] = 0.f;
                    acc[g] = MFMA16(a, Bv[g][0], ci);
                }
            }
            // prefetch next step's gx (consumed next iteration; no forced drain)
            {
                const int tn = (t < 127) ? t + 1 : 127;
                const int ln = d ? 127 - tn : tn;
                const _Float16* gp = gxf + (size_t)(d * 128 + ln) * 13312 + lane * 4 + bg;
                #pragma unroll
                for (int g = 0; g < 4; ++g) gx0[g] = gp[(g * 13 + w) * 256];
            }
            #pragma unroll
            for (int kf = 1; kf < 4; ++kf) {
                s16x8 a = *(const s16x8*)(hcur + kf * 512 + lane * 8);
                #pragma unroll
                for (int g = 0; g < 4; ++g) acc[g] = MFMA16(a, Bv[g][kf], acc[g]);
            }
            {   // kf = 4 : gates 0-1 regs, gates 2-3 LDS
                s16x8 a = *(const s16x8*)(hcur + 4 * 512 + lane * 8);
                acc[0] = MFMA16(a, Bv4[0], acc[0]);
                acc[1] = MFMA16(a, Bv4[1], acc[1]);
                #pragma unroll
                for (int g = 2; g < 4; ++g) {
                    s16x8 b = *(const s16x8*)(Bl + (size_t)(104 + w * 2 + (g - 2)) * 512 + lane * 8);
                    acc[g] = MFMA16(a, b, acc[g]);
                }
            }
            #pragma unroll
            for (int kk = 0; kk < 2; ++kk) {   // kf = 5,6 from LDS
                s16x8 a = *(const s16x8*)(hcur + (5 + kk) * 512 + lane * 8);
                #pragma unroll
                for (int g = 0; g < 4; ++g) {
                    s16x8 b = *(const s16x8*)(Bl + (size_t)(((w * 4 + g) * 2 + kk)) * 512 + lane * 8);
                    acc[g] = MFMA16(a, b, acc[g]);
                }
            }

            PHASE2(acc, cs0, hv0, w)

            BARLDS();
        }
    } else {
        __syncthreads();
        for (int t = 0; t < 128; ++t) BARLDS();
    }
}

// ---------------- span pack ------------------------------------------------
// 1024 blocks = 16 b x 64 chunks of 126 spans. Two 128-thread halves work
// alternating spans (i,j wave-uniform); zero tail is one contiguous fill.
__global__ __launch_bounds__(256) void k_span(
    const float* __restrict__ hf, const float* __restrict__ hb,
    const int* __restrict__ lens, float* __restrict__ out)
{
    const int b  = blockIdx.x >> 6;
    const int nb = blockIdx.x & 63;
    const int tid = threadIdx.x;
    const int s0 = nb * 126;
    const int s1 = (s0 + 126 < 8001) ? s0 + 126 : 8001;
    const int len = lens[b];
    const int M = len - 2;
    const int np = M * (M + 1) / 2;

    const int h = tid >> 7, tl = tid & 127;

    // compute phase: spans s in [s0, min(s1,np)), half h takes s0+h, s0+h+2, ...
    const int cend = (s1 < np) ? s1 : np;
    for (int s = s0 + h; s < cend; s += 2) {
        float disc = (float)((2 * M + 1) * (2 * M + 1) - 8 * s);
        int i = (int)(((float)(2 * M + 1) - sqrtf(disc)) * 0.5f);
        if (i < 0) i = 0;
        if (i > M - 1) i = M - 1;
        #define PREF(x) ((x) * M - (x) * ((x) - 1) / 2)
        while (i > 0 && PREF(i) > s) --i;
        while (PREF(i + 1) <= s) ++i;
        int j = i + 1 + (s - PREF(i));
        #undef PREF

        if (tl < 100) {
            f32x4* orow = (f32x4*)(out + ((size_t)b * 8001 + s) * 400);
            f32x4 aa, bb;
            if (tl < 50) {
                aa = ((const f32x4*)(hf + (size_t)(b * 128 + j) * 200))[tl];
                bb = ((const f32x4*)(hf + (size_t)(b * 128 + i) * 200))[tl];
            } else {
                int t2 = tl - 50;
                aa = ((const f32x4*)(hb + (size_t)(b * 128 + i + 1) * 200))[t2];
                bb = ((const f32x4*)(hb + (size_t)(b * 128 + j + 1) * 200))[t2];
            }
            f32x4 rr = aa - bb;
            __builtin_nontemporal_store(rr, orow + tl);
        }
    }

    // zero phase: spans [max(s0,np), s1) as one contiguous f32x4 fill
    int zs = (s0 > np) ? s0 : np;
    if (zs < s1) {
        f32x4 z = 0.f;
        f32x4* zp = (f32x4*)(out + ((size_t)b * 8001 + zs) * 400);
        const int cnt = (s1 - zs) * 100;     // f32x4 count
        for (int idx = tid; idx < cnt; idx += 256)
            __builtin_nontemporal_store(z, zp + idx);
    }
}

// ---------------------------------------------------------------------------
extern "C" void kernel_launch(void* const* d_in, const int* in_sizes, int n_in,
                              void* d_out, int out_size, void* d_ws, size_t ws_size,
                              hipStream_t stream)
{
    const float* ext  = (const float*)d_in[0];
    const float* wrd  = (const float*)d_in[1];
    const float* pos  = (const float*)d_in[2];
    const float* dep  = (const float*)d_in[3];
    const float* ent  = (const float*)d_in[4];
    const float* iob  = (const float*)d_in[5];
    const float* wih0 = (const float*)d_in[6];
    const float* whh0 = (const float*)d_in[7];
    const float* bih0 = (const float*)d_in[8];
    const float* bhh0 = (const float*)d_in[9];
    const float* wih1 = (const float*)d_in[10];
    const float* whh1 = (const float*)d_in[11];
    const float* bih1 = (const float*)d_in[12];
    const float* bhh1 = (const float*)d_in[13];
    const float* bert = (const float*)d_in[14];
    const int* wi = (const int*)d_in[15];
    const int* pi = (const int*)d_in[16];
    const int* di = (const int*)d_in[17];
    const int* ei = (const int*)d_in[18];
    const int* ii = (const int*)d_in[19];
    float* out = (float*)d_out;

    char* ws = (char*)d_ws;
    unsigned short* emb    = (unsigned short*)(ws + 0);          // 5,111,808
    unsigned short* wih0b  = (unsigned short*)(ws + 5111808);    // 4,153,344
    unsigned short* wih1b  = (unsigned short*)(ws + 9265152);    // 1,384,448
    unsigned short* whh0p  = (unsigned short*)(ws + 10649600);   //   745,472
    unsigned short* whh1p  = (unsigned short*)(ws + 11395072);   //   745,472
    float*          bias0p = (float*)(ws + 12140544);            //     6,656
    float*          bias1p = (float*)(ws + 12147200);            //     6,656
    int*            lens   = (int*)(ws + 12153856);              //        64
    _Float16*       gxf0   = (_Float16*)(ws + 12153920);         // 6,815,744
    _Float16*       gxf1   = (_Float16*)(ws + 18969664);         // 6,815,744
    unsigned short* out0b  = (unsigned short*)(ws + 25785408);   // 1,703,936
    float*          hfv    = (float*)(ws + 27489344);            // 1,638,400
    float*          hbv    = (float*)(ws + 29127744);            // 1,638,400 (end 30,766,144)

    (void)hipFuncSetAttribute((const void*)k_rec,
                              hipFuncAttributeMaxDynamicSharedMemorySize, 147968);

    k_prep<<<5819, 256, 0, stream>>>(ext, wrd, pos, dep, ent, iob, bert,
                                     wi, pi, di, ei, ii, emb,
                                     wih0, wih0b, wih1, wih1b,
                                     whh0, whh0p, whh1, whh1p,
                                     bih0, bhh0, bias0p, bih1, bhh1, bias1p,
                                     lens, out + 51206400, out0b);

    k_gemm<<<832, 256, 0, stream>>>(emb, wih0b, bias0p, gxf0, 1248, 39);
    k_rec <<<8, 1024, 147968, stream>>>(gxf0, whh0p, wi, out0b, nullptr, nullptr);
    k_gemm<<<832, 256, 0, stream>>>(out0b, wih1b, bias1p, gxf1, 416, 13);
    k_rec <<<8, 1024, 147968, stream>>>(gxf1, whh1p, wi, nullptr, hfv, hbv);
    k_span<<<16 * 64, 256, 0, stream>>>(hfv, hbv, lens, out);
}